// Round 1
// baseline (338.523 us; speedup 1.0000x reference)
//
#include <hip/hip_runtime.h>
#include <math.h>

#define Bc 2
#define Nc 2048
#define Ec 512
#define Hc 8
#define Dc 64
#define Mc 4096   // B*N
#define NT 32     // chunks per sequence
#define Cc 64     // chunk size

// ---------------------------------------------------------------------------
// gamma per head: 1 - exp(linspace(log(1/32), log(1/512), 8))
__device__ __forceinline__ float get_gamma(int h) {
    const float l0 = -3.4657359028f;   // log(1/32)
    const float l1 = -6.2383246250f;   // log(1/512)
    return 1.0f - expf(l0 + (l1 - l0) * ((float)h / 7.0f));
}

// ---------------------------------------------------------------------------
// xpos tables: sinS = sin*scale, cosS = cos*scale, sinIS = sin/scale, cosIS = cos/scale
// tables are [N][32]
__global__ __launch_bounds__(256) void tables_kernel(float* __restrict__ sinS,
                                                     float* __restrict__ cosS,
                                                     float* __restrict__ sinIS,
                                                     float* __restrict__ cosIS) {
    int idx = blockIdx.x * 256 + threadIdx.x;   // 0 .. N*32-1
    if (idx >= Nc * 32) return;
    int n = idx >> 5;
    int i = idx & 31;
    // xscale = (2i + 0.4*64) / (1.4*64)
    float xscale = (2.0f * (float)i + 25.6f) / 89.6f;
    float power  = ((float)n - 1024.0f) / 512.0f;   // (n + min_pos)/512, min_pos=-1024
    float scale  = powf(xscale, power);
    float inv_freq = powf(10000.0f, -(float)i / 32.0f);
    float ang = (float)n * inv_freq;
    float s = sinf(ang), c = cosf(ang);
    sinS[idx]  = s * scale;
    cosS[idx]  = c * scale;
    float rs = 1.0f / scale;
    sinIS[idx] = s * rs;
    cosIS[idx] = c * rs;
}

// ---------------------------------------------------------------------------
// Generic fp32 GEMM  C[r][c] = sum_k X[r][k] * W[c][k] (+ bias[c]), tiled 128x128,
// 256 threads, 8x8 micro-tile per thread (2x2 blocks of 4x4).
// mode: 0=Q (xpos*scale -> Qr BHND), 1=K (xpos/scale, /8 -> Kr BHND),
//       2=V (-> Vr BHND), 3=G (silu -> G BNE), 4=final (-> Out BNE)
__global__ __launch_bounds__(256) void gemm_kernel(
    const float* __restrict__ Xq, const float* __restrict__ Xk, const float* __restrict__ Xv,
    const float* __restrict__ XretG,
    const float* __restrict__ Wq, const float* __restrict__ Wk, const float* __restrict__ Wv,
    const float* __restrict__ Wg, const float* __restrict__ Wo,
    const float* __restrict__ bq, const float* __restrict__ bk, const float* __restrict__ bv,
    const float* __restrict__ bg, const float* __restrict__ bo,
    float* __restrict__ Qr, float* __restrict__ Kr, float* __restrict__ Vr,
    float* __restrict__ G, float* __restrict__ Out,
    const float* __restrict__ sinS, const float* __restrict__ cosS,
    const float* __restrict__ sinIS, const float* __restrict__ cosIS,
    int mode_base)
{
    int mode = mode_base + blockIdx.z;
    const float* X; const float* W; const float* bias;
    switch (mode) {
        case 0:  X = Xq;    W = Wq; bias = bq; break;
        case 1:  X = Xk;    W = Wk; bias = bk; break;
        case 2:  X = Xv;    W = Wv; bias = bv; break;
        case 3:  X = Xq;    W = Wg; bias = bg; break;
        default: X = XretG; W = Wo; bias = bo; break;
    }

    __shared__ float Xs[16][132];   // [k][m], pad 4 -> conflict-free, 16B-aligned rows
    __shared__ float Wt[16][132];   // [k][n]

    int tid = threadIdx.x;
    int tx = tid & 15, ty = tid >> 4;
    int row0 = blockIdx.x * 128;
    int col0 = blockIdx.y * 128;

    float acc[2][2][4][4];
    #pragma unroll
    for (int a = 0; a < 2; ++a)
        #pragma unroll
        for (int b = 0; b < 2; ++b)
            #pragma unroll
            for (int i = 0; i < 4; ++i)
                #pragma unroll
                for (int j = 0; j < 4; ++j) acc[a][b][i][j] = 0.0f;

    for (int k0 = 0; k0 < Ec; k0 += 16) {
        #pragma unroll
        for (int i = 0; i < 2; ++i) {
            int f  = tid + i * 256;        // 0..511 float4 slots
            int r  = f >> 2;               // 0..127 tile row
            int kc = (f & 3) << 2;         // 0,4,8,12
            float4 xv = *(const float4*)&X[(row0 + r) * Ec + k0 + kc];
            Xs[kc + 0][r] = xv.x; Xs[kc + 1][r] = xv.y;
            Xs[kc + 2][r] = xv.z; Xs[kc + 3][r] = xv.w;
            float4 wv = *(const float4*)&W[(col0 + r) * Ec + k0 + kc];
            Wt[kc + 0][r] = wv.x; Wt[kc + 1][r] = wv.y;
            Wt[kc + 2][r] = wv.z; Wt[kc + 3][r] = wv.w;
        }
        __syncthreads();
        #pragma unroll
        for (int k = 0; k < 16; ++k) {
            float4 a0 = *(const float4*)&Xs[k][ty * 4];
            float4 a1 = *(const float4*)&Xs[k][64 + ty * 4];
            float4 b0 = *(const float4*)&Wt[k][tx * 4];
            float4 b1 = *(const float4*)&Wt[k][64 + tx * 4];
            float av[2][4] = {{a0.x, a0.y, a0.z, a0.w}, {a1.x, a1.y, a1.z, a1.w}};
            float bv2[2][4] = {{b0.x, b0.y, b0.z, b0.w}, {b1.x, b1.y, b1.z, b1.w}};
            #pragma unroll
            for (int im = 0; im < 2; ++im)
                #pragma unroll
                for (int ii = 0; ii < 4; ++ii)
                    #pragma unroll
                    for (int in = 0; in < 2; ++in)
                        #pragma unroll
                        for (int jj = 0; jj < 4; ++jj)
                            acc[im][in][ii][jj] = fmaf(av[im][ii], bv2[in][jj], acc[im][in][ii][jj]);
        }
        __syncthreads();
    }

    // epilogue
    #pragma unroll
    for (int im = 0; im < 2; ++im) {
        #pragma unroll
        for (int ii = 0; ii < 4; ++ii) {
            int r  = row0 + im * 64 + ty * 4 + ii;
            int bb = r >> 11;          // / 2048
            int n  = r & 2047;
            #pragma unroll
            for (int in = 0; in < 2; ++in) {
                int c = col0 + in * 64 + tx * 4;
                float x0 = acc[im][in][ii][0] + bias[c + 0];
                float x1 = acc[im][in][ii][1] + bias[c + 1];
                float x2 = acc[im][in][ii][2] + bias[c + 2];
                float x3 = acc[im][in][ii][3] + bias[c + 3];
                if (mode == 0 || mode == 1) {
                    int h = c >> 6, d = c & 63;
                    int i2 = d >> 1;                      // even d -> pair index
                    const float* st = (mode == 0) ? sinS : sinIS;
                    const float* ct = (mode == 0) ? cosS : cosIS;
                    float s0 = st[n * 32 + i2],     c0 = ct[n * 32 + i2];
                    float s1 = st[n * 32 + i2 + 1], c1 = ct[n * 32 + i2 + 1];
                    float y0 = x0 * c0 - x1 * s0;
                    float y1 = x1 * c0 + x0 * s0;
                    float y2 = x2 * c1 - x3 * s1;
                    float y3 = x3 * c1 + x2 * s1;
                    if (mode == 1) { y0 *= 0.125f; y1 *= 0.125f; y2 *= 0.125f; y3 *= 0.125f; }
                    float* dst = (mode == 0) ? Qr : Kr;
                    float4 o = {y0, y1, y2, y3};
                    *(float4*)&dst[(((bb * Hc + h) * Nc) + n) * Dc + d] = o;
                } else if (mode == 2) {
                    int h = c >> 6, d = c & 63;
                    float4 o = {x0, x1, x2, x3};
                    *(float4*)&Vr[(((bb * Hc + h) * Nc) + n) * Dc + d] = o;
                } else if (mode == 3) {
                    float4 o = {x0 / (1.0f + expf(-x0)), x1 / (1.0f + expf(-x1)),
                                x2 / (1.0f + expf(-x2)), x3 / (1.0f + expf(-x3))};
                    *(float4*)&G[r * Ec + c] = o;
                } else {
                    float4 o = {x0, x1, x2, x3};
                    *(float4*)&Out[r * Ec + c] = o;
                }
            }
        }
    }
}

// ---------------------------------------------------------------------------
// Phase A: per (bh, chunk) local state  L[dk][dv] = sum_s gamma^(64-s) K[s][dk] V[s][dv]
__global__ __launch_bounds__(256) void phaseA_kernel(const float* __restrict__ Kr,
                                                     const float* __restrict__ Vr,
                                                     float* __restrict__ L)
{
    int bh = blockIdx.x;      // 0..15
    int t  = blockIdx.y;      // 0..31
    float gamma = get_gamma(bh & 7);
    float lg = logf(gamma);

    __shared__ float Ks[64][68];   // [s][dk], decay folded
    __shared__ float Vs[64][68];   // [s][dv]

    int tid = threadIdx.x;
    const float* Kc = Kr + (bh * Nc + t * Cc) * Dc;
    const float* Vc = Vr + (bh * Nc + t * Cc) * Dc;

    #pragma unroll
    for (int i = 0; i < 4; ++i) {
        int f = tid + i * 256;          // 0..1023 float4 slots
        int s = f >> 4;                 // 0..63
        int d = (f & 15) << 2;
        float w = expf(lg * (float)(Cc - s));     // gamma^(64-s)
        float4 kv = *(const float4*)&Kc[s * Dc + d];
        float4 ks = {kv.x * w, kv.y * w, kv.z * w, kv.w * w};
        *(float4*)&Ks[s][d] = ks;
        float4 vv = *(const float4*)&Vc[s * Dc + d];
        *(float4*)&Vs[s][d] = vv;
    }
    __syncthreads();

    int tx = tid & 15, ty = tid >> 4;
    float acc[4][4];
    #pragma unroll
    for (int i = 0; i < 4; ++i)
        #pragma unroll
        for (int j = 0; j < 4; ++j) acc[i][j] = 0.0f;

    for (int s = 0; s < 64; ++s) {
        float4 a = *(const float4*)&Ks[s][ty * 4];
        float4 b = *(const float4*)&Vs[s][tx * 4];
        float av[4] = {a.x, a.y, a.z, a.w};
        float bv[4] = {b.x, b.y, b.z, b.w};
        #pragma unroll
        for (int i = 0; i < 4; ++i)
            #pragma unroll
            for (int j = 0; j < 4; ++j)
                acc[i][j] = fmaf(av[i], bv[j], acc[i][j]);
    }

    float* Lp = L + (bh * NT + t) * 4096;
    #pragma unroll
    for (int i = 0; i < 4; ++i) {
        float4 o = {acc[i][0], acc[i][1], acc[i][2], acc[i][3]};
        *(float4*)&Lp[(ty * 4 + i) * 64 + tx * 4] = o;
    }
}

// ---------------------------------------------------------------------------
// Phase B: scan over chunks. S_t written BEFORE folding chunk t in:
//   S_0 = 0 ; S_{t+1} = gamma^64 * S_t + L_t
__global__ __launch_bounds__(256) void scan_kernel(const float* __restrict__ L,
                                                   float* __restrict__ Sst)
{
    int bh = blockIdx.x;
    int tid = threadIdx.x;
    float gamma = get_gamma(bh & 7);
    float g64 = expf(logf(gamma) * 64.0f);

    float4 s[4];
    #pragma unroll
    for (int i = 0; i < 4; ++i) s[i] = {0.0f, 0.0f, 0.0f, 0.0f};

    const float* Lp = L + bh * NT * 4096;
    float* Sp = Sst + bh * NT * 4096;
    for (int t = 0; t < NT; ++t) {
        #pragma unroll
        for (int i = 0; i < 4; ++i) {
            int off = t * 4096 + i * 1024 + tid * 4;
            *(float4*)&Sp[off] = s[i];
            float4 l = *(const float4*)&Lp[off];
            s[i].x = s[i].x * g64 + l.x;
            s[i].y = s[i].y * g64 + l.y;
            s[i].z = s[i].z * g64 + l.z;
            s[i].w = s[i].w * g64 + l.w;
        }
    }
}

// ---------------------------------------------------------------------------
// Phase C: per (bh, chunk): O = (tril(QK^T decayed)) @ V + gamma^i * Q @ S,
// then LayerNorm over D, multiply by gate, write to (B,N,E) layout.
__global__ __launch_bounds__(256) void phaseC_kernel(
    const float* __restrict__ Qr, const float* __restrict__ Kr, const float* __restrict__ Vr,
    const float* __restrict__ Sst, const float* __restrict__ G, float* __restrict__ retG)
{
    int bh = blockIdx.x, t = blockIdx.y;
    int b = bh >> 3, h = bh & 7;
    float gamma = get_gamma(h);
    float lg = logf(gamma);

    __shared__ float QsT[64][68];   // [d][i]  (gamma^i folded); later reused as Vs [j][dv]
    __shared__ float KsT[64][68];   // [d][j]  (gamma^-j folded); later reused as AsT [j][i]
    __shared__ float Ss[64][68];    // [dk][dv]

    int tid = threadIdx.x;
    const float* Qc = Qr + (bh * Nc + t * Cc) * Dc;
    const float* Kc = Kr + (bh * Nc + t * Cc) * Dc;
    const float* Sp = Sst + (bh * NT + t) * 4096;

    #pragma unroll
    for (int i = 0; i < 4; ++i) {
        int f = tid + i * 256;
        int r = f >> 4;              // chunk row / state row
        int d = (f & 15) << 2;
        float wq = expf(lg * (float)r);     // gamma^i
        float4 q = *(const float4*)&Qc[r * Dc + d];
        QsT[d + 0][r] = q.x * wq; QsT[d + 1][r] = q.y * wq;
        QsT[d + 2][r] = q.z * wq; QsT[d + 3][r] = q.w * wq;
        float wk = expf(-lg * (float)r);    // gamma^-j
        float4 kk = *(const float4*)&Kc[r * Dc + d];
        KsT[d + 0][r] = kk.x * wk; KsT[d + 1][r] = kk.y * wk;
        KsT[d + 2][r] = kk.z * wk; KsT[d + 3][r] = kk.w * wk;
        float4 sv = *(const float4*)&Sp[r * 64 + d];
        *(float4*)&Ss[r][d] = sv;
    }
    __syncthreads();

    int tx = tid & 15, ty = tid >> 4;
    float accA[4][4], accO[4][4];
    #pragma unroll
    for (int i = 0; i < 4; ++i)
        #pragma unroll
        for (int j = 0; j < 4; ++j) { accA[i][j] = 0.0f; accO[i][j] = 0.0f; }

    for (int d = 0; d < 64; ++d) {
        float4 a  = *(const float4*)&QsT[d][ty * 4];   // Q rows i
        float4 kb = *(const float4*)&KsT[d][tx * 4];   // K rows j
        float4 sb = *(const float4*)&Ss[d][tx * 4];    // S cols dv
        float av[4] = {a.x, a.y, a.z, a.w};
        float kv[4] = {kb.x, kb.y, kb.z, kb.w};
        float sv[4] = {sb.x, sb.y, sb.z, sb.w};
        #pragma unroll
        for (int i = 0; i < 4; ++i)
            #pragma unroll
            for (int j = 0; j < 4; ++j) {
                accA[i][j] = fmaf(av[i], kv[j], accA[i][j]);
                accO[i][j] = fmaf(av[i], sv[j], accO[i][j]);
            }
    }
    __syncthreads();

    // write masked A^T into KsT space; load V into QsT space (row-major)
    #pragma unroll
    for (int i = 0; i < 4; ++i) {
        int gi = ty * 4 + i;
        #pragma unroll
        for (int j = 0; j < 4; ++j) {
            int gj = tx * 4 + j;
            KsT[gj][gi] = (gj <= gi) ? accA[i][j] : 0.0f;   // AsT[j][i]
        }
    }
    const float* Vc = Vr + (bh * Nc + t * Cc) * Dc;
    #pragma unroll
    for (int i = 0; i < 4; ++i) {
        int f = tid + i * 256;
        int r = f >> 4;
        int d = (f & 15) << 2;
        float4 vv = *(const float4*)&Vc[r * Dc + d];
        *(float4*)&QsT[r][d] = vv;     // Vs[j][dv]
    }
    __syncthreads();

    for (int j = 0; j < 64; ++j) {
        float4 a = *(const float4*)&KsT[j][ty * 4];    // AsT[j][rows i]
        float4 v = *(const float4*)&QsT[j][tx * 4];    // Vs[j][cols dv]
        float av[4] = {a.x, a.y, a.z, a.w};
        float vv[4] = {v.x, v.y, v.z, v.w};
        #pragma unroll
        for (int i = 0; i < 4; ++i)
            #pragma unroll
            for (int jj = 0; jj < 4; ++jj)
                accO[i][jj] = fmaf(av[i], vv[jj], accO[i][jj]);
    }

    // LayerNorm over D=64 per row i (row spread across 16 tx lanes)
    #pragma unroll
    for (int i = 0; i < 4; ++i) {
        float sum = accO[i][0] + accO[i][1] + accO[i][2] + accO[i][3];
        float sq  = accO[i][0] * accO[i][0] + accO[i][1] * accO[i][1]
                  + accO[i][2] * accO[i][2] + accO[i][3] * accO[i][3];
        #pragma unroll
        for (int m = 1; m < 16; m <<= 1) {
            sum += __shfl_xor(sum, m, 64);
            sq  += __shfl_xor(sq,  m, 64);
        }
        float mean = sum * (1.0f / 64.0f);
        float var  = sq * (1.0f / 64.0f) - mean * mean;
        float rinv = rsqrtf(var + 1e-6f);
        #pragma unroll
        for (int jj = 0; jj < 4; ++jj)
            accO[i][jj] = (accO[i][jj] - mean) * rinv;
    }

    // gate multiply + store to (B, N, E)
    #pragma unroll
    for (int i = 0; i < 4; ++i) {
        int n = t * Cc + ty * 4 + i;
        int idx = (b * Nc + n) * Ec + h * Dc + tx * 4;
        float4 g = *(const float4*)&G[idx];
        float4 o = {accO[i][0] * g.x, accO[i][1] * g.y,
                    accO[i][2] * g.z, accO[i][3] * g.w};
        *(float4*)&retG[idx] = o;
    }
}

// ---------------------------------------------------------------------------
extern "C" void kernel_launch(void* const* d_in, const int* in_sizes, int n_in,
                              void* d_out, int out_size, void* d_ws, size_t ws_size,
                              hipStream_t stream) {
    const float* query = (const float*)d_in[0];
    const float* key   = (const float*)d_in[1];
    const float* value = (const float*)d_in[2];
    const float* Wq = (const float*)d_in[3];
    const float* bq = (const float*)d_in[4];
    const float* Wk = (const float*)d_in[5];
    const float* bk = (const float*)d_in[6];
    const float* Wv = (const float*)d_in[7];
    const float* bv = (const float*)d_in[8];
    const float* Wg = (const float*)d_in[9];
    const float* bg = (const float*)d_in[10];
    const float* Wo = (const float*)d_in[11];
    const float* bo = (const float*)d_in[12];
    float* out = (float*)d_out;

    float* wsf  = (float*)d_ws;
    const int SZ = Bc * Nc * Ec;            // 2,097,152
    float* Qr   = wsf;                      // (B,H,N,D)
    float* Kr   = Qr + SZ;
    float* Vr   = Kr + SZ;
    float* G    = Vr + SZ;                  // (B,N,E)
    float* retG = G + SZ;                   // (B,N,E)
    float* L    = retG + SZ;                // 16*32*4096
    float* Sst  = L + SZ;
    float* tab  = Sst + SZ;
    float* sinS  = tab;
    float* cosS  = sinS + Nc * 32;
    float* sinIS = cosS + Nc * 32;
    float* cosIS = sinIS + Nc * 32;

    tables_kernel<<<dim3((Nc * 32 + 255) / 256), dim3(256), 0, stream>>>(sinS, cosS, sinIS, cosIS);

    // fused Q/K/V/G projections (mode = blockIdx.z)
    gemm_kernel<<<dim3(Mc / 128, Ec / 128, 4), dim3(256), 0, stream>>>(
        query, key, value, retG, Wq, Wk, Wv, Wg, Wo, bq, bk, bv, bg, bo,
        Qr, Kr, Vr, G, out, sinS, cosS, sinIS, cosIS, 0);

    phaseA_kernel<<<dim3(Bc * Hc, NT), dim3(256), 0, stream>>>(Kr, Vr, L);
    scan_kernel<<<dim3(Bc * Hc), dim3(256), 0, stream>>>(L, Sst);
    phaseC_kernel<<<dim3(Bc * Hc, NT), dim3(256), 0, stream>>>(Qr, Kr, Vr, Sst, G, retG);

    // final: out = retG @ Wo^T + bo
    gemm_kernel<<<dim3(Mc / 128, Ec / 128, 1), dim3(256), 0, stream>>>(
        query, key, value, retG, Wq, Wk, Wv, Wg, Wo, bq, bk, bv, bg, bo,
        Qr, Kr, Vr, G, out, sinS, cosS, sinIS, cosIS, 4);
}

// Round 2
// 205.252 us; speedup vs baseline: 1.6493x; 1.6493x over previous
//
#include <hip/hip_runtime.h>
#include <math.h>

#define Bc 2
#define Nc 2048
#define Ec 512
#define Hc 8
#define Dc 64
#define Mc 4096   // B*N
#define NT 32     // chunks per sequence
#define Cc 64     // chunk size

typedef short bf16x8 __attribute__((ext_vector_type(8)));
typedef float f32x4 __attribute__((ext_vector_type(4)));

// global -> LDS direct DMA, 16B per lane, dest = wave-uniform base + lane*16
#define GLOAD(g, l) __builtin_amdgcn_global_load_lds(                        \
    (const __attribute__((address_space(1))) unsigned*)(const void*)(g),     \
    (__attribute__((address_space(3))) unsigned*)(void*)(l), 16, 0, 0)

__device__ __forceinline__ unsigned short f2bf(float x) {
    union { float f; unsigned u; } v; v.f = x;
    unsigned r = v.u + 0x7fffu + ((v.u >> 16) & 1u);   // RNE
    return (unsigned short)(r >> 16);
}
__device__ __forceinline__ float bf2f(unsigned short b) {
    union { float f; unsigned u; } v; v.u = ((unsigned)b) << 16;
    return v.f;
}

// gamma per head: 1 - exp(linspace(log(1/32), log(1/512), 8))
__device__ __forceinline__ float get_gamma(int h) {
    const float l0 = -3.4657359028f;
    const float l1 = -6.2383246250f;
    return 1.0f - expf(l0 + (l1 - l0) * ((float)h / 7.0f));
}

// ---------------------------------------------------------------------------
// xpos tables [N][32]: sinS=sin*scale, cosS=cos*scale, sinIS=sin/scale, cosIS=cos/scale
__global__ __launch_bounds__(256) void tables_kernel(float* __restrict__ sinS,
                                                     float* __restrict__ cosS,
                                                     float* __restrict__ sinIS,
                                                     float* __restrict__ cosIS) {
    int idx = blockIdx.x * 256 + threadIdx.x;
    if (idx >= Nc * 32) return;
    int n = idx >> 5;
    int i = idx & 31;
    float xscale = (2.0f * (float)i + 25.6f) / 89.6f;
    float power  = ((float)n - 1024.0f) / 512.0f;
    float scale  = powf(xscale, power);
    float inv_freq = powf(10000.0f, -(float)i / 32.0f);
    float ang = (float)n * inv_freq;
    float s = sinf(ang), c = cosf(ang);
    sinS[idx]  = s * scale;
    cosS[idx]  = c * scale;
    float rs = 1.0f / scale;
    sinIS[idx] = s * rs;
    cosIS[idx] = c * rs;
}

// ---------------------------------------------------------------------------
// split fp32 arrays into bf16 hi/lo pairs
struct SplitArgs {
    const float* src[8];
    unsigned short* hi[8];
    unsigned short* lo[8];
    int n[8];
};

__global__ __launch_bounds__(256) void split_kernel(SplitArgs a) {
    int arr = blockIdx.y;
    int i4 = (blockIdx.x * 256 + threadIdx.x) * 4;
    if (i4 >= a.n[arr]) return;
    float4 v = *(const float4*)&a.src[arr][i4];
    ushort4 h, l;
    h.x = f2bf(v.x); l.x = f2bf(v.x - bf2f(h.x));
    h.y = f2bf(v.y); l.y = f2bf(v.y - bf2f(h.y));
    h.z = f2bf(v.z); l.z = f2bf(v.z - bf2f(h.z));
    h.w = f2bf(v.w); l.w = f2bf(v.w - bf2f(h.w));
    *(ushort4*)&a.hi[arr][i4] = h;
    *(ushort4*)&a.lo[arr][i4] = l;
}

// ---------------------------------------------------------------------------
// bf16x3 MFMA GEMM: C[r][c] = sum_k X[r][k]*W[c][k] + bias[c], 128x128 tile,
// BK=32, 4 waves, each wave owns a 64x64 subtile (4x4 fragments of 16x16).
// x*w ~= xh*wh + xh*wl + xl*wh  (fp32 MFMA accumulate)
// mode: 0=Q (xpos*scale), 1=K (xpos/scale, /8), 2=V, 3=G (silu), 4=final
__global__ __launch_bounds__(256) void mgemm_kernel(
    const unsigned short* __restrict__ Xq_h, const unsigned short* __restrict__ Xq_l,
    const unsigned short* __restrict__ Xk_h, const unsigned short* __restrict__ Xk_l,
    const unsigned short* __restrict__ Xv_h, const unsigned short* __restrict__ Xv_l,
    const unsigned short* __restrict__ Xr_h, const unsigned short* __restrict__ Xr_l,
    const unsigned short* __restrict__ Wq_h, const unsigned short* __restrict__ Wq_l,
    const unsigned short* __restrict__ Wk_h, const unsigned short* __restrict__ Wk_l,
    const unsigned short* __restrict__ Wv_h, const unsigned short* __restrict__ Wv_l,
    const unsigned short* __restrict__ Wg_h, const unsigned short* __restrict__ Wg_l,
    const unsigned short* __restrict__ Wo_h, const unsigned short* __restrict__ Wo_l,
    const float* __restrict__ bq, const float* __restrict__ bk, const float* __restrict__ bv,
    const float* __restrict__ bg, const float* __restrict__ bo,
    float* __restrict__ Qr, float* __restrict__ Kr, float* __restrict__ Vr,
    float* __restrict__ G, float* __restrict__ Out,
    const float* __restrict__ sinS, const float* __restrict__ cosS,
    const float* __restrict__ sinIS, const float* __restrict__ cosIS,
    int mode_base)
{
    int mode = mode_base + blockIdx.z;
    const unsigned short *Xh, *Xl, *Wh, *Wl; const float* bias;
    switch (mode) {
        case 0:  Xh = Xq_h; Xl = Xq_l; Wh = Wq_h; Wl = Wq_l; bias = bq; break;
        case 1:  Xh = Xk_h; Xl = Xk_l; Wh = Wk_h; Wl = Wk_l; bias = bk; break;
        case 2:  Xh = Xv_h; Xl = Xv_l; Wh = Wv_h; Wl = Wv_l; bias = bv; break;
        case 3:  Xh = Xq_h; Xl = Xq_l; Wh = Wg_h; Wl = Wg_l; bias = bg; break;
        default: Xh = Xr_h; Xl = Xr_l; Wh = Wo_h; Wl = Wo_l; bias = bo; break;
    }

    // 4 tiles of 128 rows x 32 k (bf16): Ahi, Alo, Bhi, Blo. 8 KB each, 32 KB total.
    // layout: slot-linear, slot q = r*4 + s (16B slots), s XOR-swizzled via source.
    __shared__ __align__(16) short lds[4 * 4096];

    int tid  = threadIdx.x;
    int lane = tid & 63;
    int w    = tid >> 6;
    int wr   = w >> 1, wc = w & 1;
    int row0 = blockIdx.x * 128, col0 = blockIdx.y * 128;
    int lrow = lane & 15, lslot = lane >> 4;

    f32x4 acc[4][4];
    #pragma unroll
    for (int i = 0; i < 4; ++i)
        #pragma unroll
        for (int j = 0; j < 4; ++j) acc[i][j] = {0.f, 0.f, 0.f, 0.f};

    // fragment LDS short-offsets (swizzled): lane reads row r, k-slot lslot
    int aoff[4], boff[4];
    #pragma unroll
    for (int mi = 0; mi < 4; ++mi) {
        int r = wr * 64 + mi * 16 + lrow;
        aoff[mi] = (r * 4 + (lslot ^ ((r >> 1) & 3))) * 8;
    }
    #pragma unroll
    for (int ni = 0; ni < 4; ++ni) {
        int r = wc * 64 + ni * 16 + lrow;
        boff[ni] = (r * 4 + (lslot ^ ((r >> 1) & 3))) * 8;
    }

    for (int k0 = 0; k0 < Ec; k0 += 32) {
        // stage: per array 512 slots of 16B; 256 threads x 2 rounds
        #pragma unroll
        for (int i = 0; i < 2; ++i) {
            int q = i * 256 + tid;
            int r = q >> 2;
            int sp = (q & 3) ^ ((r >> 1) & 3);      // pre-swizzled source slot
            int base = (i * 256 + (w << 6)) * 8;    // wave-uniform dest (shorts)
            size_t ga = (size_t)(row0 + r) * Ec + k0 + sp * 8;
            size_t gb = (size_t)(col0 + r) * Ec + k0 + sp * 8;
            GLOAD(Xh + ga, &lds[base]);
            GLOAD(Xl + ga, &lds[4096 + base]);
            GLOAD(Wh + gb, &lds[8192 + base]);
            GLOAD(Wl + gb, &lds[12288 + base]);
        }
        __syncthreads();

        bf16x8 ah[4], al[4], bh[4], bl[4];
        #pragma unroll
        for (int mi = 0; mi < 4; ++mi) {
            ah[mi] = *(const bf16x8*)&lds[aoff[mi]];
            al[mi] = *(const bf16x8*)&lds[4096 + aoff[mi]];
        }
        #pragma unroll
        for (int ni = 0; ni < 4; ++ni) {
            bh[ni] = *(const bf16x8*)&lds[8192 + boff[ni]];
            bl[ni] = *(const bf16x8*)&lds[12288 + boff[ni]];
        }
        #pragma unroll
        for (int mi = 0; mi < 4; ++mi)
            #pragma unroll
            for (int ni = 0; ni < 4; ++ni) {
                acc[mi][ni] = __builtin_amdgcn_mfma_f32_16x16x32_bf16(ah[mi], bh[ni], acc[mi][ni], 0, 0, 0);
                acc[mi][ni] = __builtin_amdgcn_mfma_f32_16x16x32_bf16(ah[mi], bl[ni], acc[mi][ni], 0, 0, 0);
                acc[mi][ni] = __builtin_amdgcn_mfma_f32_16x16x32_bf16(al[mi], bh[ni], acc[mi][ni], 0, 0, 0);
            }
        __syncthreads();
    }

    // epilogue: D[row][col]: col = lane&15, row = (lane>>4)*4 + reg
    int quad = lane >> 4;
    #pragma unroll
    for (int mi = 0; mi < 4; ++mi) {
        #pragma unroll
        for (int reg = 0; reg < 4; ++reg) {
            int R  = row0 + wr * 64 + mi * 16 + quad * 4 + reg;
            int bb = R >> 11;
            int n  = R & 2047;
            #pragma unroll
            for (int ni = 0; ni < 4; ++ni) {
                int c = col0 + wc * 64 + ni * 16 + lrow;
                float x = acc[mi][ni][reg] + bias[c];
                if (mode <= 1) {
                    float p = __shfl_xor(x, 1, 64);       // partner column c^1
                    int h = c >> 6, d = c & 63, pr = d >> 1;
                    const float* st = (mode == 0) ? sinS : sinIS;
                    const float* ct = (mode == 0) ? cosS : cosIS;
                    float sv = st[n * 32 + pr], cv = ct[n * 32 + pr];
                    float y = (c & 1) ? fmaf(x, cv,  p * sv)
                                      : fmaf(x, cv, -p * sv);
                    if (mode == 1) y *= 0.125f;
                    float* dst = (mode == 0) ? Qr : Kr;
                    dst[(((size_t)(bb * Hc + h)) * Nc + n) * Dc + d] = y;
                } else if (mode == 2) {
                    int h = c >> 6, d = c & 63;
                    Vr[(((size_t)(bb * Hc + h)) * Nc + n) * Dc + d] = x;
                } else if (mode == 3) {
                    G[(size_t)R * Ec + c] = x / (1.0f + expf(-x));
                } else {
                    Out[(size_t)R * Ec + c] = x;
                }
            }
        }
    }
}

// ---------------------------------------------------------------------------
// Phase A: per (bh, chunk) local state  L[dk][dv] = sum_s gamma^(64-s) K[s][dk] V[s][dv]
__global__ __launch_bounds__(256) void phaseA_kernel(const float* __restrict__ Kr,
                                                     const float* __restrict__ Vr,
                                                     float* __restrict__ L)
{
    int bh = blockIdx.x;
    int t  = blockIdx.y;
    float gamma = get_gamma(bh & 7);
    float lg = logf(gamma);

    __shared__ float Ks[64][68];
    __shared__ float Vs[64][68];

    int tid = threadIdx.x;
    const float* Kc = Kr + (size_t)(bh * Nc + t * Cc) * Dc;
    const float* Vc = Vr + (size_t)(bh * Nc + t * Cc) * Dc;

    #pragma unroll
    for (int i = 0; i < 4; ++i) {
        int f = tid + i * 256;
        int s = f >> 4;
        int d = (f & 15) << 2;
        float w = expf(lg * (float)(Cc - s));
        float4 kv = *(const float4*)&Kc[s * Dc + d];
        float4 ks = {kv.x * w, kv.y * w, kv.z * w, kv.w * w};
        *(float4*)&Ks[s][d] = ks;
        float4 vv = *(const float4*)&Vc[s * Dc + d];
        *(float4*)&Vs[s][d] = vv;
    }
    __syncthreads();

    int tx = tid & 15, ty = tid >> 4;
    float acc[4][4];
    #pragma unroll
    for (int i = 0; i < 4; ++i)
        #pragma unroll
        for (int j = 0; j < 4; ++j) acc[i][j] = 0.0f;

    for (int s = 0; s < 64; ++s) {
        float4 a = *(const float4*)&Ks[s][ty * 4];
        float4 b = *(const float4*)&Vs[s][tx * 4];
        float av[4] = {a.x, a.y, a.z, a.w};
        float bv[4] = {b.x, b.y, b.z, b.w};
        #pragma unroll
        for (int i = 0; i < 4; ++i)
            #pragma unroll
            for (int j = 0; j < 4; ++j)
                acc[i][j] = fmaf(av[i], bv[j], acc[i][j]);
    }

    float* Lp = L + (size_t)(bh * NT + t) * 4096;
    #pragma unroll
    for (int i = 0; i < 4; ++i) {
        float4 o = {acc[i][0], acc[i][1], acc[i][2], acc[i][3]};
        *(float4*)&Lp[(ty * 4 + i) * 64 + tx * 4] = o;
    }
}

// ---------------------------------------------------------------------------
// Phase B: S_0 = 0 ; S_{t+1} = gamma^64 * S_t + L_t  (S_t written pre-fold)
__global__ __launch_bounds__(256) void scan_kernel(const float* __restrict__ L,
                                                   float* __restrict__ Sst)
{
    int bh = blockIdx.x;
    int tid = threadIdx.x;
    float gamma = get_gamma(bh & 7);
    float g64 = expf(logf(gamma) * 64.0f);

    float4 s[4];
    #pragma unroll
    for (int i = 0; i < 4; ++i) s[i] = {0.0f, 0.0f, 0.0f, 0.0f};

    const float* Lp = L + (size_t)bh * NT * 4096;
    float* Sp = Sst + (size_t)bh * NT * 4096;
    for (int t = 0; t < NT; ++t) {
        #pragma unroll
        for (int i = 0; i < 4; ++i) {
            int off = t * 4096 + i * 1024 + tid * 4;
            *(float4*)&Sp[off] = s[i];
            float4 l = *(const float4*)&Lp[off];
            s[i].x = s[i].x * g64 + l.x;
            s[i].y = s[i].y * g64 + l.y;
            s[i].z = s[i].z * g64 + l.z;
            s[i].w = s[i].w * g64 + l.w;
        }
    }
}

// ---------------------------------------------------------------------------
// Phase C: O = tril-decayed(QK^T) @ V + gamma^i * Q @ S, LayerNorm, gate,
// write retG as bf16 hi/lo in (B,N,E) layout.
__global__ __launch_bounds__(256) void phaseC_kernel(
    const float* __restrict__ Qr, const float* __restrict__ Kr, const float* __restrict__ Vr,
    const float* __restrict__ Sst, const float* __restrict__ G,
    unsigned short* __restrict__ retGh, unsigned short* __restrict__ retGl)
{
    int bh = blockIdx.x, t = blockIdx.y;
    int b = bh >> 3, h = bh & 7;
    float gamma = get_gamma(h);
    float lg = logf(gamma);

    __shared__ float QsT[64][68];
    __shared__ float KsT[64][68];
    __shared__ float Ss[64][68];

    int tid = threadIdx.x;
    const float* Qc = Qr + (size_t)(bh * Nc + t * Cc) * Dc;
    const float* Kc = Kr + (size_t)(bh * Nc + t * Cc) * Dc;
    const float* Sp = Sst + (size_t)(bh * NT + t) * 4096;

    #pragma unroll
    for (int i = 0; i < 4; ++i) {
        int f = tid + i * 256;
        int r = f >> 4;
        int d = (f & 15) << 2;
        float wq = expf(lg * (float)r);
        float4 q = *(const float4*)&Qc[r * Dc + d];
        QsT[d + 0][r] = q.x * wq; QsT[d + 1][r] = q.y * wq;
        QsT[d + 2][r] = q.z * wq; QsT[d + 3][r] = q.w * wq;
        float wk = expf(-lg * (float)r);
        float4 kk = *(const float4*)&Kc[r * Dc + d];
        KsT[d + 0][r] = kk.x * wk; KsT[d + 1][r] = kk.y * wk;
        KsT[d + 2][r] = kk.z * wk; KsT[d + 3][r] = kk.w * wk;
        float4 sv = *(const float4*)&Sp[r * 64 + d];
        *(float4*)&Ss[r][d] = sv;
    }
    __syncthreads();

    int tx = tid & 15, ty = tid >> 4;
    float accA[4][4], accO[4][4];
    #pragma unroll
    for (int i = 0; i < 4; ++i)
        #pragma unroll
        for (int j = 0; j < 4; ++j) { accA[i][j] = 0.0f; accO[i][j] = 0.0f; }

    for (int d = 0; d < 64; ++d) {
        float4 a  = *(const float4*)&QsT[d][ty * 4];
        float4 kb = *(const float4*)&KsT[d][tx * 4];
        float4 sb = *(const float4*)&Ss[d][tx * 4];
        float av[4] = {a.x, a.y, a.z, a.w};
        float kv[4] = {kb.x, kb.y, kb.z, kb.w};
        float sv[4] = {sb.x, sb.y, sb.z, sb.w};
        #pragma unroll
        for (int i = 0; i < 4; ++i)
            #pragma unroll
            for (int j = 0; j < 4; ++j) {
                accA[i][j] = fmaf(av[i], kv[j], accA[i][j]);
                accO[i][j] = fmaf(av[i], sv[j], accO[i][j]);
            }
    }
    __syncthreads();

    #pragma unroll
    for (int i = 0; i < 4; ++i) {
        int gi = ty * 4 + i;
        #pragma unroll
        for (int j = 0; j < 4; ++j) {
            int gj = tx * 4 + j;
            KsT[gj][gi] = (gj <= gi) ? accA[i][j] : 0.0f;
        }
    }
    const float* Vc = Vr + (size_t)(bh * Nc + t * Cc) * Dc;
    #pragma unroll
    for (int i = 0; i < 4; ++i) {
        int f = tid + i * 256;
        int r = f >> 4;
        int d = (f & 15) << 2;
        float4 vv = *(const float4*)&Vc[r * Dc + d];
        *(float4*)&QsT[r][d] = vv;
    }
    __syncthreads();

    for (int j = 0; j < 64; ++j) {
        float4 a = *(const float4*)&KsT[j][ty * 4];
        float4 v = *(const float4*)&QsT[j][tx * 4];
        float av[4] = {a.x, a.y, a.z, a.w};
        float vv[4] = {v.x, v.y, v.z, v.w};
        #pragma unroll
        for (int i = 0; i < 4; ++i)
            #pragma unroll
            for (int jj = 0; jj < 4; ++jj)
                accO[i][jj] = fmaf(av[i], vv[jj], accO[i][jj]);
    }

    // LayerNorm over D=64 per row (row spread across 16 tx lanes)
    #pragma unroll
    for (int i = 0; i < 4; ++i) {
        float sum = accO[i][0] + accO[i][1] + accO[i][2] + accO[i][3];
        float sq  = accO[i][0] * accO[i][0] + accO[i][1] * accO[i][1]
                  + accO[i][2] * accO[i][2] + accO[i][3] * accO[i][3];
        #pragma unroll
        for (int m = 1; m < 16; m <<= 1) {
            sum += __shfl_xor(sum, m, 64);
            sq  += __shfl_xor(sq,  m, 64);
        }
        float mean = sum * (1.0f / 64.0f);
        float var  = sq * (1.0f / 64.0f) - mean * mean;
        float rinv = rsqrtf(var + 1e-6f);
        #pragma unroll
        for (int jj = 0; jj < 4; ++jj)
            accO[i][jj] = (accO[i][jj] - mean) * rinv;
    }

    // gate multiply + hi/lo bf16 store to (B, N, E)
    #pragma unroll
    for (int i = 0; i < 4; ++i) {
        int n = t * Cc + ty * 4 + i;
        size_t idx = ((size_t)b * Nc + n) * Ec + h * Dc + tx * 4;
        float4 g = *(const float4*)&G[idx];
        float o0 = accO[i][0] * g.x, o1 = accO[i][1] * g.y;
        float o2 = accO[i][2] * g.z, o3 = accO[i][3] * g.w;
        ushort4 hh, ll;
        hh.x = f2bf(o0); ll.x = f2bf(o0 - bf2f(hh.x));
        hh.y = f2bf(o1); ll.y = f2bf(o1 - bf2f(hh.y));
        hh.z = f2bf(o2); ll.z = f2bf(o2 - bf2f(hh.z));
        hh.w = f2bf(o3); ll.w = f2bf(o3 - bf2f(hh.w));
        *(ushort4*)&retGh[idx] = hh;
        *(ushort4*)&retGl[idx] = ll;
    }
}

// ---------------------------------------------------------------------------
extern "C" void kernel_launch(void* const* d_in, const int* in_sizes, int n_in,
                              void* d_out, int out_size, void* d_ws, size_t ws_size,
                              hipStream_t stream) {
    const float* query = (const float*)d_in[0];
    const float* key   = (const float*)d_in[1];
    const float* value = (const float*)d_in[2];
    const float* Wq = (const float*)d_in[3];
    const float* bq = (const float*)d_in[4];
    const float* Wk = (const float*)d_in[5];
    const float* bk = (const float*)d_in[6];
    const float* Wv = (const float*)d_in[7];
    const float* bv = (const float*)d_in[8];
    const float* Wg = (const float*)d_in[9];
    const float* bg = (const float*)d_in[10];
    const float* Wo = (const float*)d_in[11];
    const float* bo = (const float*)d_in[12];
    float* out = (float*)d_out;

    float* wsf = (float*)d_ws;
    const size_t SZ = (size_t)Bc * Nc * Ec;   // 2,097,152

    float* Qr = wsf;                 // fp32 (B,H,N,D)
    float* Kr = Qr + SZ;
    float* Vr = Kr + SZ;
    float* G  = Vr + SZ;             // fp32 (B,N,E)

    // X hi/lo region [4SZ, 7SZ) floats — dead after fused GEMM, then reused:
    unsigned short* Xq_h = (unsigned short*)(wsf + 4 * SZ);
    unsigned short* Xq_l = Xq_h + SZ;
    unsigned short* Xk_h = Xq_l + SZ;
    unsigned short* Xk_l = Xk_h + SZ;
    unsigned short* Xv_h = Xk_l + SZ;
    unsigned short* Xv_l = Xv_h + SZ;
    float* L   = wsf + 4 * SZ;                       // overlays Xq (after GEMM)
    float* Sst = wsf + 5 * SZ;                       // overlays Xk
    unsigned short* retGh = (unsigned short*)(wsf + 6 * SZ);  // overlays Xv
    unsigned short* retGl = retGh + SZ;

    const size_t WSZ = (size_t)Ec * Ec;      // 262,144
    unsigned short* Wp = (unsigned short*)(wsf + 7 * SZ);
    unsigned short* Wq_h = Wp;            unsigned short* Wq_l = Wp + WSZ;
    unsigned short* Wk_h = Wp + 2 * WSZ;  unsigned short* Wk_l = Wp + 3 * WSZ;
    unsigned short* Wv_h = Wp + 4 * WSZ;  unsigned short* Wv_l = Wp + 5 * WSZ;
    unsigned short* Wg_h = Wp + 6 * WSZ;  unsigned short* Wg_l = Wp + 7 * WSZ;
    unsigned short* Wo_h = Wp + 8 * WSZ;  unsigned short* Wo_l = Wp + 9 * WSZ;

    float* tab = wsf + 7 * SZ + (10 * WSZ) / 2;
    float* sinS  = tab;
    float* cosS  = sinS + Nc * 32;
    float* sinIS = cosS + Nc * 32;
    float* cosIS = sinIS + Nc * 32;

    tables_kernel<<<dim3((Nc * 32 + 255) / 256), dim3(256), 0, stream>>>(sinS, cosS, sinIS, cosIS);

    SplitArgs sa;
    sa.src[0] = query; sa.hi[0] = Xq_h; sa.lo[0] = Xq_l; sa.n[0] = (int)SZ;
    sa.src[1] = key;   sa.hi[1] = Xk_h; sa.lo[1] = Xk_l; sa.n[1] = (int)SZ;
    sa.src[2] = value; sa.hi[2] = Xv_h; sa.lo[2] = Xv_l; sa.n[2] = (int)SZ;
    sa.src[3] = Wq;    sa.hi[3] = Wq_h; sa.lo[3] = Wq_l; sa.n[3] = (int)WSZ;
    sa.src[4] = Wk;    sa.hi[4] = Wk_h; sa.lo[4] = Wk_l; sa.n[4] = (int)WSZ;
    sa.src[5] = Wv;    sa.hi[5] = Wv_h; sa.lo[5] = Wv_l; sa.n[5] = (int)WSZ;
    sa.src[6] = Wg;    sa.hi[6] = Wg_h; sa.lo[6] = Wg_l; sa.n[6] = (int)WSZ;
    sa.src[7] = Wo;    sa.hi[7] = Wo_h; sa.lo[7] = Wo_l; sa.n[7] = (int)WSZ;
    split_kernel<<<dim3(2048, 8), dim3(256), 0, stream>>>(sa);

    // fused Q/K/V/G projections
    mgemm_kernel<<<dim3(Mc / 128, Ec / 128, 4), dim3(256), 0, stream>>>(
        Xq_h, Xq_l, Xk_h, Xk_l, Xv_h, Xv_l, retGh, retGl,
        Wq_h, Wq_l, Wk_h, Wk_l, Wv_h, Wv_l, Wg_h, Wg_l, Wo_h, Wo_l,
        bq, bk, bv, bg, bo, Qr, Kr, Vr, G, out,
        sinS, cosS, sinIS, cosIS, 0);

    phaseA_kernel<<<dim3(Bc * Hc, NT), dim3(256), 0, stream>>>(Kr, Vr, L);
    scan_kernel<<<dim3(Bc * Hc), dim3(256), 0, stream>>>(L, Sst);
    phaseC_kernel<<<dim3(Bc * Hc, NT), dim3(256), 0, stream>>>(Qr, Kr, Vr, Sst, G, retGh, retGl);

    // final: out = retG @ Wo^T + bo
    mgemm_kernel<<<dim3(Mc / 128, Ec / 128, 1), dim3(256), 0, stream>>>(
        Xq_h, Xq_l, Xk_h, Xk_l, Xv_h, Xv_l, retGh, retGl,
        Wq_h, Wq_l, Wk_h, Wk_l, Wv_h, Wv_l, Wg_h, Wg_l, Wo_h, Wo_l,
        bq, bk, bv, bg, bo, Qr, Kr, Vr, G, out,
        sinS, cosS, sinIS, cosIS, 4);
}

// Round 3
// 185.701 us; speedup vs baseline: 1.8229x; 1.1053x over previous
//
#include <hip/hip_runtime.h>
#include <math.h>

#define Bc 2
#define Nc 2048
#define Ec 512
#define Hc 8
#define Dc 64
#define Mc 4096   // B*N
#define NT 32     // chunks per sequence
#define Cc 64     // chunk size

typedef short bf16x8 __attribute__((ext_vector_type(8)));
typedef float f32x4 __attribute__((ext_vector_type(4)));

// global -> LDS direct DMA, 16B per lane, dest = wave-uniform base + lane*16
#define GLOAD(g, l) __builtin_amdgcn_global_load_lds(                        \
    (const __attribute__((address_space(1))) unsigned*)(const void*)(g),     \
    (__attribute__((address_space(3))) unsigned*)(void*)(l), 16, 0, 0)

__device__ __forceinline__ unsigned short f2bf(float x) {
    union { float f; unsigned u; } v; v.f = x;
    unsigned r = v.u + 0x7fffu + ((v.u >> 16) & 1u);   // RNE
    return (unsigned short)(r >> 16);
}
__device__ __forceinline__ float bf2f(unsigned short b) {
    union { float f; unsigned u; } v; v.u = ((unsigned)b) << 16;
    return v.f;
}

// gamma per head: 1 - exp(linspace(log(1/32), log(1/512), 8))
__device__ __forceinline__ float get_gamma(int h) {
    const float l0 = -3.4657359028f;
    const float l1 = -6.2383246250f;
    return 1.0f - expf(l0 + (l1 - l0) * ((float)h / 7.0f));
}

// ---------------------------------------------------------------------------
// xpos tables [N][32]
__global__ __launch_bounds__(256) void tables_kernel(float* __restrict__ sinS,
                                                     float* __restrict__ cosS,
                                                     float* __restrict__ sinIS,
                                                     float* __restrict__ cosIS) {
    int idx = blockIdx.x * 256 + threadIdx.x;
    if (idx >= Nc * 32) return;
    int n = idx >> 5;
    int i = idx & 31;
    float xscale = (2.0f * (float)i + 25.6f) / 89.6f;
    float power  = ((float)n - 1024.0f) / 512.0f;
    float scale  = powf(xscale, power);
    float inv_freq = powf(10000.0f, -(float)i / 32.0f);
    float ang = (float)n * inv_freq;
    float s = sinf(ang), c = cosf(ang);
    sinS[idx]  = s * scale;
    cosS[idx]  = c * scale;
    float rs = 1.0f / scale;
    sinIS[idx] = s * rs;
    cosIS[idx] = c * rs;
}

// ---------------------------------------------------------------------------
// split fp32 arrays into bf16 hi/lo pairs
struct SplitArgs {
    const float* src[8];
    unsigned short* hi[8];
    unsigned short* lo[8];
    int n[8];
};

__global__ __launch_bounds__(256) void split_kernel(SplitArgs a) {
    int arr = blockIdx.y;
    int i4 = (blockIdx.x * 256 + threadIdx.x) * 4;
    if (i4 >= a.n[arr]) return;
    float4 v = *(const float4*)&a.src[arr][i4];
    ushort4 h, l;
    h.x = f2bf(v.x); l.x = f2bf(v.x - bf2f(h.x));
    h.y = f2bf(v.y); l.y = f2bf(v.y - bf2f(h.y));
    h.z = f2bf(v.z); l.z = f2bf(v.z - bf2f(h.z));
    h.w = f2bf(v.w); l.w = f2bf(v.w - bf2f(h.w));
    *(ushort4*)&a.hi[arr][i4] = h;
    *(ushort4*)&a.lo[arr][i4] = l;
}

// ---------------------------------------------------------------------------
// bf16x3 MFMA GEMM: C[r][c] = sum_k X[r][k]*W[c][k] + bias[c], TMxTN tile,
// BK=32, 4 waves (2x2), wave owns (TM/2)x(TN/2). x*w ~= xh*wh + xh*wl + xl*wh.
// mode: 0=Q (xpos*scale), 1=K (xpos/scale, /8), 2=V, 3=G (silu), 4=final
template<int TM, int TN>
__global__ __launch_bounds__(256) void mgemm_kernel(
    const unsigned short* __restrict__ Xq_h, const unsigned short* __restrict__ Xq_l,
    const unsigned short* __restrict__ Xk_h, const unsigned short* __restrict__ Xk_l,
    const unsigned short* __restrict__ Xv_h, const unsigned short* __restrict__ Xv_l,
    const unsigned short* __restrict__ Xr_h, const unsigned short* __restrict__ Xr_l,
    const unsigned short* __restrict__ Wq_h, const unsigned short* __restrict__ Wq_l,
    const unsigned short* __restrict__ Wk_h, const unsigned short* __restrict__ Wk_l,
    const unsigned short* __restrict__ Wv_h, const unsigned short* __restrict__ Wv_l,
    const unsigned short* __restrict__ Wg_h, const unsigned short* __restrict__ Wg_l,
    const unsigned short* __restrict__ Wo_h, const unsigned short* __restrict__ Wo_l,
    const float* __restrict__ bq, const float* __restrict__ bk, const float* __restrict__ bv,
    const float* __restrict__ bg, const float* __restrict__ bo,
    float* __restrict__ Qr, float* __restrict__ Kr, float* __restrict__ Vr,
    float* __restrict__ G, float* __restrict__ Out,
    const float* __restrict__ sinS, const float* __restrict__ cosS,
    const float* __restrict__ sinIS, const float* __restrict__ cosIS,
    int mode_base)
{
    constexpr int MI = TM / 32;     // frags per wave (m)
    constexpr int NI = TN / 32;     // frags per wave (n)

    int mode = mode_base + blockIdx.z;
    const unsigned short *Xh, *Xl, *Wh, *Wl; const float* bias;
    switch (mode) {
        case 0:  Xh = Xq_h; Xl = Xq_l; Wh = Wq_h; Wl = Wq_l; bias = bq; break;
        case 1:  Xh = Xk_h; Xl = Xk_l; Wh = Wk_h; Wl = Wk_l; bias = bk; break;
        case 2:  Xh = Xv_h; Xl = Xv_l; Wh = Wv_h; Wl = Wv_l; bias = bv; break;
        case 3:  Xh = Xq_h; Xl = Xq_l; Wh = Wg_h; Wl = Wg_l; bias = bg; break;
        default: Xh = Xr_h; Xl = Xr_l; Wh = Wo_h; Wl = Wo_l; bias = bo; break;
    }

    // LDS: Ah | Al | Bh | Bl, each T*32 shorts, slot-linear (16B slots),
    // k-slot XOR-swizzled via pre-swizzled global source (rule #21).
    __shared__ __align__(16) short lds[(TM + TN) * 64];
    constexpr int AL = TM * 32;     // Al offset (shorts)
    constexpr int BH = TM * 64;     // Bh offset
    constexpr int BL = TM * 64 + TN * 32;

    int tid  = threadIdx.x;
    int lane = tid & 63;
    int w    = tid >> 6;
    int wr   = w >> 1, wc = w & 1;
    int row0 = blockIdx.x * TM, col0 = blockIdx.y * TN;
    int lrow = lane & 15, lslot = lane >> 4;

    f32x4 acc[MI][NI];
    #pragma unroll
    for (int i = 0; i < MI; ++i)
        #pragma unroll
        for (int j = 0; j < NI; ++j) acc[i][j] = {0.f, 0.f, 0.f, 0.f};

    int aoff[MI], boff[NI];
    #pragma unroll
    for (int mi = 0; mi < MI; ++mi) {
        int r = wr * (TM / 2) + mi * 16 + lrow;
        aoff[mi] = (r * 4 + (lslot ^ ((r >> 1) & 3))) * 8;
    }
    #pragma unroll
    for (int ni = 0; ni < NI; ++ni) {
        int r = wc * (TN / 2) + ni * 16 + lrow;
        boff[ni] = (r * 4 + (lslot ^ ((r >> 1) & 3))) * 8;
    }

    for (int k0 = 0; k0 < Ec; k0 += 32) {
        #pragma unroll
        for (int i = 0; i < TM / 64; ++i) {
            int q = i * 256 + tid;
            int r = q >> 2;
            int sp = (q & 3) ^ ((r >> 1) & 3);
            int base = (i * 256 + (w << 6)) * 8;
            size_t ga = (size_t)(row0 + r) * Ec + k0 + sp * 8;
            GLOAD(Xh + ga, &lds[base]);
            GLOAD(Xl + ga, &lds[AL + base]);
        }
        #pragma unroll
        for (int i = 0; i < TN / 64; ++i) {
            int q = i * 256 + tid;
            int r = q >> 2;
            int sp = (q & 3) ^ ((r >> 1) & 3);
            int base = (i * 256 + (w << 6)) * 8;
            size_t gb = (size_t)(col0 + r) * Ec + k0 + sp * 8;
            GLOAD(Wh + gb, &lds[BH + base]);
            GLOAD(Wl + gb, &lds[BL + base]);
        }
        __syncthreads();

        bf16x8 ah[MI], al[MI], bh[NI], bl[NI];
        #pragma unroll
        for (int mi = 0; mi < MI; ++mi) {
            ah[mi] = *(const bf16x8*)&lds[aoff[mi]];
            al[mi] = *(const bf16x8*)&lds[AL + aoff[mi]];
        }
        #pragma unroll
        for (int ni = 0; ni < NI; ++ni) {
            bh[ni] = *(const bf16x8*)&lds[BH + boff[ni]];
            bl[ni] = *(const bf16x8*)&lds[BL + boff[ni]];
        }
        #pragma unroll
        for (int mi = 0; mi < MI; ++mi)
            #pragma unroll
            for (int ni = 0; ni < NI; ++ni) {
                acc[mi][ni] = __builtin_amdgcn_mfma_f32_16x16x32_bf16(ah[mi], bh[ni], acc[mi][ni], 0, 0, 0);
                acc[mi][ni] = __builtin_amdgcn_mfma_f32_16x16x32_bf16(ah[mi], bl[ni], acc[mi][ni], 0, 0, 0);
                acc[mi][ni] = __builtin_amdgcn_mfma_f32_16x16x32_bf16(al[mi], bh[ni], acc[mi][ni], 0, 0, 0);
            }
        __syncthreads();
    }

    // epilogue: D[row][col]: col = lane&15, row = (lane>>4)*4 + reg
    int quad = lane >> 4;
    #pragma unroll
    for (int mi = 0; mi < MI; ++mi) {
        #pragma unroll
        for (int reg = 0; reg < 4; ++reg) {
            int R  = row0 + wr * (TM / 2) + mi * 16 + quad * 4 + reg;
            int bb = R >> 11;
            int n  = R & 2047;
            #pragma unroll
            for (int ni = 0; ni < NI; ++ni) {
                int c = col0 + wc * (TN / 2) + ni * 16 + lrow;
                float x = acc[mi][ni][reg] + bias[c];
                if (mode <= 1) {
                    float p = __shfl_xor(x, 1, 64);       // partner column c^1
                    int h = c >> 6, d = c & 63, pr = d >> 1;
                    const float* st = (mode == 0) ? sinS : sinIS;
                    const float* ct = (mode == 0) ? cosS : cosIS;
                    float sv = st[n * 32 + pr], cv = ct[n * 32 + pr];
                    float y = (c & 1) ? fmaf(x, cv,  p * sv)
                                      : fmaf(x, cv, -p * sv);
                    if (mode == 1) y *= 0.125f;
                    float* dst = (mode == 0) ? Qr : Kr;
                    dst[(((size_t)(bb * Hc + h)) * Nc + n) * Dc + d] = y;
                } else if (mode == 2) {
                    int h = c >> 6, d = c & 63;
                    Vr[(((size_t)(bb * Hc + h)) * Nc + n) * Dc + d] = x;
                } else if (mode == 3) {
                    G[(size_t)R * Ec + c] = x / (1.0f + expf(-x));
                } else {
                    Out[(size_t)R * Ec + c] = x;
                }
            }
        }
    }
}

// ---------------------------------------------------------------------------
// Phase A: per (bh, chunk) local state  L[dk][dv] = sum_s gamma^(64-s) K[s][dk] V[s][dv]
__global__ __launch_bounds__(256) void phaseA_kernel(const float* __restrict__ Kr,
                                                     const float* __restrict__ Vr,
                                                     float* __restrict__ L)
{
    int bh = blockIdx.x;
    int t  = blockIdx.y;
    float gamma = get_gamma(bh & 7);
    float lg = logf(gamma);

    __shared__ float Ks[64][68];
    __shared__ float Vs[64][68];

    int tid = threadIdx.x;
    const float* Kc = Kr + (size_t)(bh * Nc + t * Cc) * Dc;
    const float* Vc = Vr + (size_t)(bh * Nc + t * Cc) * Dc;

    #pragma unroll
    for (int i = 0; i < 4; ++i) {
        int f = tid + i * 256;
        int s = f >> 4;
        int d = (f & 15) << 2;
        float w = expf(lg * (float)(Cc - s));
        float4 kv = *(const float4*)&Kc[s * Dc + d];
        float4 ks = {kv.x * w, kv.y * w, kv.z * w, kv.w * w};
        *(float4*)&Ks[s][d] = ks;
        float4 vv = *(const float4*)&Vc[s * Dc + d];
        *(float4*)&Vs[s][d] = vv;
    }
    __syncthreads();

    int tx = tid & 15, ty = tid >> 4;
    float acc[4][4];
    #pragma unroll
    for (int i = 0; i < 4; ++i)
        #pragma unroll
        for (int j = 0; j < 4; ++j) acc[i][j] = 0.0f;

    for (int s = 0; s < 64; ++s) {
        float4 a = *(const float4*)&Ks[s][ty * 4];
        float4 b = *(const float4*)&Vs[s][tx * 4];
        float av[4] = {a.x, a.y, a.z, a.w};
        float bv[4] = {b.x, b.y, b.z, b.w};
        #pragma unroll
        for (int i = 0; i < 4; ++i)
            #pragma unroll
            for (int j = 0; j < 4; ++j)
                acc[i][j] = fmaf(av[i], bv[j], acc[i][j]);
    }

    float* Lp = L + (size_t)(bh * NT + t) * 4096;
    #pragma unroll
    for (int i = 0; i < 4; ++i) {
        float4 o = {acc[i][0], acc[i][1], acc[i][2], acc[i][3]};
        *(float4*)&Lp[(ty * 4 + i) * 64 + tx * 4] = o;
    }
}

// ---------------------------------------------------------------------------
// Phase B: S_0 = 0 ; S_{t+1} = gamma^64 * S_t + L_t  (S_t written pre-fold)
// grid (16, 4): each block owns one 1024-float quarter of the 64x64 state.
__global__ __launch_bounds__(256) void scan_kernel(const float* __restrict__ L,
                                                   float* __restrict__ Sst)
{
    int bh = blockIdx.x;
    int part = blockIdx.y;
    int tid = threadIdx.x;
    float gamma = get_gamma(bh & 7);
    float g64 = expf(logf(gamma) * 64.0f);

    float4 s = {0.0f, 0.0f, 0.0f, 0.0f};
    size_t base = (size_t)bh * NT * 4096 + part * 1024 + tid * 4;
    const float* Lp = L + base;
    float* Sp = Sst + base;
    for (int t = 0; t < NT; ++t) {
        *(float4*)&Sp[(size_t)t * 4096] = s;
        float4 l = *(const float4*)&Lp[(size_t)t * 4096];
        s.x = s.x * g64 + l.x;
        s.y = s.y * g64 + l.y;
        s.z = s.z * g64 + l.z;
        s.w = s.w * g64 + l.w;
    }
}

// ---------------------------------------------------------------------------
// Phase C: O = tril-decayed(QK^T) @ V + gamma^i * Q @ S, LayerNorm, gate,
// write retG as bf16 hi/lo in (B,N,E) layout.
__global__ __launch_bounds__(256) void phaseC_kernel(
    const float* __restrict__ Qr, const float* __restrict__ Kr, const float* __restrict__ Vr,
    const float* __restrict__ Sst, const float* __restrict__ G,
    unsigned short* __restrict__ retGh, unsigned short* __restrict__ retGl)
{
    int bh = blockIdx.x, t = blockIdx.y;
    int b = bh >> 3, h = bh & 7;
    float gamma = get_gamma(h);
    float lg = logf(gamma);

    __shared__ float QsT[64][68];
    __shared__ float KsT[64][68];
    __shared__ float Ss[64][68];

    int tid = threadIdx.x;
    const float* Qc = Qr + (size_t)(bh * Nc + t * Cc) * Dc;
    const float* Kc = Kr + (size_t)(bh * Nc + t * Cc) * Dc;
    const float* Sp = Sst + (size_t)(bh * NT + t) * 4096;

    #pragma unroll
    for (int i = 0; i < 4; ++i) {
        int f = tid + i * 256;
        int r = f >> 4;
        int d = (f & 15) << 2;
        float wq = expf(lg * (float)r);
        float4 q = *(const float4*)&Qc[r * Dc + d];
        QsT[d + 0][r] = q.x * wq; QsT[d + 1][r] = q.y * wq;
        QsT[d + 2][r] = q.z * wq; QsT[d + 3][r] = q.w * wq;
        float wk = expf(-lg * (float)r);
        float4 kk = *(const float4*)&Kc[r * Dc + d];
        KsT[d + 0][r] = kk.x * wk; KsT[d + 1][r] = kk.y * wk;
        KsT[d + 2][r] = kk.z * wk; KsT[d + 3][r] = kk.w * wk;
        float4 sv = *(const float4*)&Sp[r * 64 + d];
        *(float4*)&Ss[r][d] = sv;
    }
    __syncthreads();

    int tx = tid & 15, ty = tid >> 4;
    float accA[4][4], accO[4][4];
    #pragma unroll
    for (int i = 0; i < 4; ++i)
        #pragma unroll
        for (int j = 0; j < 4; ++j) { accA[i][j] = 0.0f; accO[i][j] = 0.0f; }

    for (int d = 0; d < 64; ++d) {
        float4 a  = *(const float4*)&QsT[d][ty * 4];
        float4 kb = *(const float4*)&KsT[d][tx * 4];
        float4 sb = *(const float4*)&Ss[d][tx * 4];
        float av[4] = {a.x, a.y, a.z, a.w};
        float kv[4] = {kb.x, kb.y, kb.z, kb.w};
        float sv[4] = {sb.x, sb.y, sb.z, sb.w};
        #pragma unroll
        for (int i = 0; i < 4; ++i)
            #pragma unroll
            for (int j = 0; j < 4; ++j) {
                accA[i][j] = fmaf(av[i], kv[j], accA[i][j]);
                accO[i][j] = fmaf(av[i], sv[j], accO[i][j]);
            }
    }
    __syncthreads();

    #pragma unroll
    for (int i = 0; i < 4; ++i) {
        int gi = ty * 4 + i;
        #pragma unroll
        for (int j = 0; j < 4; ++j) {
            int gj = tx * 4 + j;
            KsT[gj][gi] = (gj <= gi) ? accA[i][j] : 0.0f;
        }
    }
    const float* Vc = Vr + (size_t)(bh * Nc + t * Cc) * Dc;
    #pragma unroll
    for (int i = 0; i < 4; ++i) {
        int f = tid + i * 256;
        int r = f >> 4;
        int d = (f & 15) << 2;
        float4 vv = *(const float4*)&Vc[r * Dc + d];
        *(float4*)&QsT[r][d] = vv;
    }
    __syncthreads();

    for (int j = 0; j < 64; ++j) {
        float4 a = *(const float4*)&KsT[j][ty * 4];
        float4 v = *(const float4*)&QsT[j][tx * 4];
        float av[4] = {a.x, a.y, a.z, a.w};
        float vv[4] = {v.x, v.y, v.z, v.w};
        #pragma unroll
        for (int i = 0; i < 4; ++i)
            #pragma unroll
            for (int jj = 0; jj < 4; ++jj)
                accO[i][jj] = fmaf(av[i], vv[jj], accO[i][jj]);
    }

    // LayerNorm over D=64 per row (row spread across 16 tx lanes)
    #pragma unroll
    for (int i = 0; i < 4; ++i) {
        float sum = accO[i][0] + accO[i][1] + accO[i][2] + accO[i][3];
        float sq  = accO[i][0] * accO[i][0] + accO[i][1] * accO[i][1]
                  + accO[i][2] * accO[i][2] + accO[i][3] * accO[i][3];
        #pragma unroll
        for (int m = 1; m < 16; m <<= 1) {
            sum += __shfl_xor(sum, m, 64);
            sq  += __shfl_xor(sq,  m, 64);
        }
        float mean = sum * (1.0f / 64.0f);
        float var  = sq * (1.0f / 64.0f) - mean * mean;
        float rinv = rsqrtf(var + 1e-6f);
        #pragma unroll
        for (int jj = 0; jj < 4; ++jj)
            accO[i][jj] = (accO[i][jj] - mean) * rinv;
    }

    // gate multiply + hi/lo bf16 store to (B, N, E)
    #pragma unroll
    for (int i = 0; i < 4; ++i) {
        int n = t * Cc + ty * 4 + i;
        size_t idx = ((size_t)b * Nc + n) * Ec + h * Dc + tx * 4;
        float4 g = *(const float4*)&G[idx];
        float o0 = accO[i][0] * g.x, o1 = accO[i][1] * g.y;
        float o2 = accO[i][2] * g.z, o3 = accO[i][3] * g.w;
        ushort4 hh, ll;
        hh.x = f2bf(o0); ll.x = f2bf(o0 - bf2f(hh.x));
        hh.y = f2bf(o1); ll.y = f2bf(o1 - bf2f(hh.y));
        hh.z = f2bf(o2); ll.z = f2bf(o2 - bf2f(hh.z));
        hh.w = f2bf(o3); ll.w = f2bf(o3 - bf2f(hh.w));
        *(ushort4*)&retGh[idx] = hh;
        *(ushort4*)&retGl[idx] = ll;
    }
}

// ---------------------------------------------------------------------------
extern "C" void kernel_launch(void* const* d_in, const int* in_sizes, int n_in,
                              void* d_out, int out_size, void* d_ws, size_t ws_size,
                              hipStream_t stream) {
    const float* query = (const float*)d_in[0];
    const float* key   = (const float*)d_in[1];
    const float* value = (const float*)d_in[2];
    const float* Wq = (const float*)d_in[3];
    const float* bq = (const float*)d_in[4];
    const float* Wk = (const float*)d_in[5];
    const float* bk = (const float*)d_in[6];
    const float* Wv = (const float*)d_in[7];
    const float* bv = (const float*)d_in[8];
    const float* Wg = (const float*)d_in[9];
    const float* bg = (const float*)d_in[10];
    const float* Wo = (const float*)d_in[11];
    const float* bo = (const float*)d_in[12];
    float* out = (float*)d_out;

    float* wsf = (float*)d_ws;
    const size_t SZ = (size_t)Bc * Nc * Ec;   // 2,097,152

    float* Qr = wsf;                 // fp32 (B,H,N,D)
    float* Kr = Qr + SZ;
    float* Vr = Kr + SZ;
    float* G  = Vr + SZ;             // fp32 (B,N,E)

    // X hi/lo region [4SZ, 7SZ) floats — dead after fused GEMM, then reused:
    unsigned short* Xq_h = (unsigned short*)(wsf + 4 * SZ);
    unsigned short* Xq_l = Xq_h + SZ;
    unsigned short* Xk_h = Xq_l + SZ;
    unsigned short* Xk_l = Xk_h + SZ;
    unsigned short* Xv_h = Xk_l + SZ;
    unsigned short* Xv_l = Xv_h + SZ;
    float* L   = wsf + 4 * SZ;                       // overlays Xq (after GEMM)
    float* Sst = wsf + 5 * SZ;                       // overlays Xk
    unsigned short* retGh = (unsigned short*)(wsf + 6 * SZ);  // overlays Xv
    unsigned short* retGl = retGh + SZ;

    const size_t WSZ = (size_t)Ec * Ec;      // 262,144
    unsigned short* Wp = (unsigned short*)(wsf + 7 * SZ);
    unsigned short* Wq_h = Wp;            unsigned short* Wq_l = Wp + WSZ;
    unsigned short* Wk_h = Wp + 2 * WSZ;  unsigned short* Wk_l = Wp + 3 * WSZ;
    unsigned short* Wv_h = Wp + 4 * WSZ;  unsigned short* Wv_l = Wp + 5 * WSZ;
    unsigned short* Wg_h = Wp + 6 * WSZ;  unsigned short* Wg_l = Wp + 7 * WSZ;
    unsigned short* Wo_h = Wp + 8 * WSZ;  unsigned short* Wo_l = Wp + 9 * WSZ;

    float* tab = wsf + 7 * SZ + (10 * WSZ) / 2;
    float* sinS  = tab;
    float* cosS  = sinS + Nc * 32;
    float* sinIS = cosS + Nc * 32;
    float* cosIS = sinIS + Nc * 32;

    tables_kernel<<<dim3((Nc * 32 + 255) / 256), dim3(256), 0, stream>>>(sinS, cosS, sinIS, cosIS);

    SplitArgs sa;
    sa.src[0] = query; sa.hi[0] = Xq_h; sa.lo[0] = Xq_l; sa.n[0] = (int)SZ;
    sa.src[1] = key;   sa.hi[1] = Xk_h; sa.lo[1] = Xk_l; sa.n[1] = (int)SZ;
    sa.src[2] = value; sa.hi[2] = Xv_h; sa.lo[2] = Xv_l; sa.n[2] = (int)SZ;
    sa.src[3] = Wq;    sa.hi[3] = Wq_h; sa.lo[3] = Wq_l; sa.n[3] = (int)WSZ;
    sa.src[4] = Wk;    sa.hi[4] = Wk_h; sa.lo[4] = Wk_l; sa.n[4] = (int)WSZ;
    sa.src[5] = Wv;    sa.hi[5] = Wv_h; sa.lo[5] = Wv_l; sa.n[5] = (int)WSZ;
    sa.src[6] = Wg;    sa.hi[6] = Wg_h; sa.lo[6] = Wg_l; sa.n[6] = (int)WSZ;
    sa.src[7] = Wo;    sa.hi[7] = Wo_h; sa.lo[7] = Wo_l; sa.n[7] = (int)WSZ;
    split_kernel<<<dim3(2048, 8), dim3(256), 0, stream>>>(sa);

    // fused Q/K/V/G projections: 128x64 tiles -> 1024 blocks (4/CU)
    mgemm_kernel<128, 64><<<dim3(Mc / 128, Ec / 64, 4), dim3(256), 0, stream>>>(
        Xq_h, Xq_l, Xk_h, Xk_l, Xv_h, Xv_l, retGh, retGl,
        Wq_h, Wq_l, Wk_h, Wk_l, Wv_h, Wv_l, Wg_h, Wg_l, Wo_h, Wo_l,
        bq, bk, bv, bg, bo, Qr, Kr, Vr, G, out,
        sinS, cosS, sinIS, cosIS, 0);

    phaseA_kernel<<<dim3(Bc * Hc, NT), dim3(256), 0, stream>>>(Kr, Vr, L);
    scan_kernel<<<dim3(Bc * Hc, 4), dim3(256), 0, stream>>>(L, Sst);
    phaseC_kernel<<<dim3(Bc * Hc, NT), dim3(256), 0, stream>>>(Qr, Kr, Vr, Sst, G, retGh, retGl);

    // final: out = retG @ Wo^T + bo, 64x64 tiles -> 512 blocks (2/CU)
    mgemm_kernel<64, 64><<<dim3(Mc / 64, Ec / 64, 1), dim3(256), 0, stream>>>(
        Xq_h, Xq_l, Xk_h, Xk_l, Xv_h, Xv_l, retGh, retGl,
        Wq_h, Wq_l, Wk_h, Wk_l, Wv_h, Wv_l, Wg_h, Wg_l, Wo_h, Wo_l,
        bq, bk, bv, bg, bo, Qr, Kr, Vr, G, out,
        sinS, cosS, sinIS, cosIS, 4);
}